// Round 16
// baseline (694.922 us; speedup 1.0000x reference)
//
#include <hip/hip_runtime.h>
#include <stdint.h>

#define TTOK 16384
#define NDIM 1024
#define NHID 2048
#define NEXP 8
#define TM 256
#define MAXT 136
#define SLOTCAP (2 * TTOK + NEXP * TM) /* 34816 */

typedef __attribute__((ext_vector_type(8))) short short8;
typedef __attribute__((ext_vector_type(4))) float f32x4;

__device__ __forceinline__ unsigned short f2bf(float f) {
  unsigned int u = __float_as_uint(f);
  u += 0x7FFFu + ((u >> 16) & 1u);
  return (unsigned short)(u >> 16);
}

__device__ __forceinline__ void gload16(const void* g, void* l) {
  __builtin_amdgcn_global_load_lds(
      (const __attribute__((address_space(1))) unsigned int*)g,
      (__attribute__((address_space(3))) unsigned int*)l, 16, 0, 0);
}

__device__ __forceinline__ float silu(float z) {
  return z / (1.0f + __expf(-z));
}

// ---------------------------------------------------------------------------
// k_prep: merged router + weight transpose/convert.
// Blocks 0..4095 = router; 4096..16383 = tconv.
// w1/w2 -> COMBINED wBt[e][4096][1024]: row 32g+u (u<16) = w1 col 16g+u;
// row 32g+16+u = w2 col 16g+u. w3 -> plain w3t[e][1024][2048].
// ---------------------------------------------------------------------------
__device__ __forceinline__ void router_block(int b, const float* __restrict__ x,
                                             const float* __restrict__ rw,
                                             unsigned short* __restrict__ xbf,
                                             int* __restrict__ tok_e,
                                             float* __restrict__ tok_gw) {
  int t = (b << 2) + (threadIdx.x >> 6);
  int lane = threadIdx.x & 63;
  const float4* xr = (const float4*)(x + (size_t)t * NDIM);

  float4 v[4];
  float d[NEXP];
#pragma unroll
  for (int e = 0; e < NEXP; ++e) d[e] = 0.f;

#pragma unroll
  for (int i = 0; i < 4; ++i) {
    int c = i * 64 + lane;
    v[i] = xr[c];
#pragma unroll
    for (int e = 0; e < NEXP; ++e) {
      float4 w = ((const float4*)(rw + e * NDIM))[c];
      d[e] += v[i].x * w.x + v[i].y * w.y + v[i].z * w.z + v[i].w * w.w;
    }
  }
#pragma unroll
  for (int e = 0; e < NEXP; ++e)
    for (int s = 32; s; s >>= 1) d[e] += __shfl_xor(d[e], s, 64);

  unsigned short* xo = xbf + (size_t)t * NDIM;
#pragma unroll
  for (int i = 0; i < 4; ++i) {
    int c = i * 64 + lane;
    ushort4 u;
    u.x = f2bf(v[i].x); u.y = f2bf(v[i].y); u.z = f2bf(v[i].z); u.w = f2bf(v[i].w);
    ((ushort4*)xo)[c] = u;
  }

  if (lane == 0) {
    float m = d[0];
#pragma unroll
    for (int e = 1; e < NEXP; ++e) m = fmaxf(m, d[e]);
    float ex[NEXP];
#pragma unroll
    for (int e = 0; e < NEXP; ++e) ex[e] = __expf(d[e] - m);
    int e0 = 0;
#pragma unroll
    for (int e = 1; e < NEXP; ++e) if (ex[e] > ex[e0]) e0 = e;
    int e1 = (e0 == 0) ? 1 : 0;
#pragma unroll
    for (int e = 0; e < NEXP; ++e) if (e != e0 && ex[e] > ex[e1]) e1 = e;
    float p0 = ex[e0], p1 = ex[e1];
    float inv = 1.f / (p0 + p1);
    tok_e[2 * t] = e0; tok_e[2 * t + 1] = e1;
    tok_gw[2 * t] = p0 * inv; tok_gw[2 * t + 1] = p1 * inv;
  }
}

__device__ __forceinline__ void tconv_tile(const float* __restrict__ src,
                                           unsigned short* __restrict__ dst,
                                           int R, int C, int bx, int by, int mode) {
  __shared__ unsigned short tile[64][65];
  int tx = threadIdx.x & 15, ty = threadIdx.x >> 4;
#pragma unroll
  for (int rr = 0; rr < 4; ++rr) {
    int rl = rr * 16 + ty;
    float4 v = *(const float4*)(src + (size_t)(by + rl) * C + bx + tx * 4);
    tile[rl][tx * 4 + 0] = f2bf(v.x);
    tile[rl][tx * 4 + 1] = f2bf(v.y);
    tile[rl][tx * 4 + 2] = f2bf(v.z);
    tile[rl][tx * 4 + 3] = f2bf(v.w);
  }
  __syncthreads();
#pragma unroll
  for (int rr = 0; rr < 4; ++rr) {
    int cl = rr * 16 + ty;
    ushort4 u;
    u.x = tile[tx * 4 + 0][cl];
    u.y = tile[tx * 4 + 1][cl];
    u.z = tile[tx * 4 + 2][cl];
    u.w = tile[tx * 4 + 3][cl];
    int c = bx + cl;
    size_t row;
    if (mode == 0) row = (size_t)c;
    else row = (size_t)(32 * (c >> 4) + (c & 15) + (mode == 2 ? 16 : 0));
    *(ushort4*)(dst + row * R + by + tx * 4) = u;
  }
}

__global__ void k_prep(const float* __restrict__ x, const float* __restrict__ rw,
                       unsigned short* __restrict__ xbf, int* __restrict__ tok_e,
                       float* __restrict__ tok_gw, const float* __restrict__ w1,
                       const float* __restrict__ w2, const float* __restrict__ w3,
                       unsigned short* __restrict__ wBt, unsigned short* __restrict__ w3t) {
  int b = blockIdx.x;
  if (b < 4096) {
    router_block(b, x, rw, xbf, tok_e, tok_gw);
    return;
  }
  int tcb = b - 4096;
  int bx = tcb & 31;
  int by = (tcb >> 5) & 15;
  int z = tcb >> 9;
  if (z < 16) {
    int e = z & 7;
    const float* src = (z < 8 ? w1 : w2) + (size_t)e * NDIM * NHID;
    unsigned short* dst = wBt + (size_t)e * 2 * NHID * NDIM;
    tconv_tile(src, dst, NDIM, NHID, bx * 64, by * 64, z < 8 ? 1 : 2);
  } else {
    int e = z - 16;
    const float* src = w3 + (size_t)e * NHID * NDIM;
    unsigned short* dst = w3t + (size_t)e * NHID * NDIM;
    tconv_tile(src, dst, NHID, NDIM, by * 64, bx * 64, 0);
  }
}

// ---------------------------------------------------------------------------
// Count / Offsets / Fill (frozen).
// ---------------------------------------------------------------------------
__global__ void k_count(const int* __restrict__ tok_e, unsigned int* __restrict__ counts) {
  __shared__ unsigned int h[NEXP];
  int tid = threadIdx.x;
  if (tid < NEXP) h[tid] = 0u;
  __syncthreads();
  for (int i = blockIdx.x * 256 + tid; i < 2 * TTOK; i += gridDim.x * 256)
    atomicAdd(&h[tok_e[i]], 1u);
  __syncthreads();
  if (tid < NEXP) atomicAdd(&counts[tid], h[tid]);
}

__global__ void k_offsets(const unsigned int* __restrict__ counts,
                          unsigned int* __restrict__ slotbase, unsigned int* __restrict__ cnt2,
                          unsigned int* __restrict__ tile_e, unsigned int* __restrict__ tile_m0) {
  int l = threadIdx.x;
  unsigned int c[NEXP], base[NEXP], tb[NEXP];
  unsigned int b = 0, t = 0;
#pragma unroll
  for (int e = 0; e < NEXP; ++e) {
    c[e] = counts[e];
    base[e] = b; tb[e] = t;
    unsigned int nt = (c[e] + TM - 1) / TM;
    b += nt * TM; t += nt;
  }
  if (l < NEXP) { slotbase[l] = base[l]; cnt2[l] = 0u; }
  for (int idx = l; idx < MAXT; idx += 64) {
    unsigned int te = 0xFFFFFFFFu, tm = 0;
#pragma unroll
    for (int e = 0; e < NEXP; ++e) {
      unsigned int nt = (c[e] + TM - 1) / TM;
      if ((unsigned)idx >= tb[e] && (unsigned)idx < tb[e] + nt) {
        te = (unsigned)e; tm = base[e] + ((unsigned)idx - tb[e]) * TM;
      }
    }
    tile_e[idx] = te; tile_m0[idx] = tm;
  }
}

__global__ void k_fill(const int* __restrict__ tok_e, const float* __restrict__ tok_gw,
                       const unsigned int* __restrict__ slotbase, unsigned int* __restrict__ cnt2,
                       unsigned int* __restrict__ tok_list, float* __restrict__ gate_list) {
  __shared__ unsigned int hcnt[NEXP];
  __shared__ unsigned int hbase[NEXP];
  int tid = threadIdx.x;
  int t = blockIdx.x * 256 + tid;
  if (tid < NEXP) hcnt[tid] = 0u;
  __syncthreads();
  int e0 = tok_e[2 * t], e1 = tok_e[2 * t + 1];
  float g0 = tok_gw[2 * t], g1 = tok_gw[2 * t + 1];
  unsigned int p0 = atomicAdd(&hcnt[e0], 1u);
  unsigned int p1 = atomicAdd(&hcnt[e1], 1u);
  __syncthreads();
  if (tid < NEXP) hbase[tid] = atomicAdd(&cnt2[tid], hcnt[tid]);
  __syncthreads();
  unsigned int s0 = slotbase[e0] + hbase[e0] + p0;
  unsigned int s1 = slotbase[e1] + hbase[e1] + p1;
  tok_list[s0] = (unsigned)t; gate_list[s0] = g0;
  tok_list[s1] = (unsigned)t; gate_list[s1] = g1;
}

__global__ void k_sentinel(float* __restrict__ out, float v) {
  if (threadIdx.x == 0 && blockIdx.x == 0) out[0] = v;
}

// ---------------------------------------------------------------------------
// GEMM12 (R16): m248-regime 256x256 single-B quadrant 8-phase.
// B = combined [W1||W2] interleaved at 16 cols (wBt). Per K-tile, 4 phases:
//   P1: stage A-grp0(t+1); vmcnt(6); bar; read a(mh0)+b(nh0); MFMA Q(0,0)
//   P2: stage B-grp0(t+1); vmcnt(4); bar; read b(nh1);        MFMA Q(0,1)
//   P3: stage A-grp1(t+1);          bar; read a(mh1);         MFMA Q(1,1)
//   P4: stage B-grp1(t+1);          bar;                      MFMA Q(1,0)
// Stage groups align with quadrant read-unions: A-grp g = rows with
// (row>>6)&1==g; B-grp g = rows with (row>>5)&1==g. Epilogue pairs
// (n even=XW1, n odd=XW2) -> silu mul, wave-local.
// ---------------------------------------------------------------------------
__global__ __launch_bounds__(512, 2) void k_gemm12(
    const unsigned short* __restrict__ xbf, const unsigned short* __restrict__ wBt,
    unsigned short* __restrict__ H, const unsigned int* __restrict__ tok_list,
    const unsigned int* __restrict__ tile_e, const unsigned int* __restrict__ tile_m0) {
  unsigned int e = tile_e[blockIdx.y];
  if (e > 7u) return;
  int m0 = (int)tile_m0[blockIdx.y];
  int n0c = blockIdx.x * 256;  // combined-col base

  __shared__ unsigned short As[2][256 * 64];  // 64 KiB
  __shared__ unsigned short Bs[2][256 * 64];  // 64 KiB

  int tid = threadIdx.x, w = tid >> 6, l = tid & 63;
  int rsub = tid >> 3;  // 0..63
  int swb = ((tid & 7) * 16) ^ ((rsub & 7) << 4);

  // A source pointers: group g, call c -> row 64g + 128c + rsub
  const unsigned short* aP[2][2];
#pragma unroll
  for (int g = 0; g < 2; ++g)
#pragma unroll
    for (int c = 0; c < 2; ++c) {
      int r = 64 * g + 128 * c + rsub;
      aP[g][c] = xbf + (size_t)tok_list[m0 + r] * NDIM + (swb >> 1);
    }
  // B source pointers: group g, call c -> row 32g + 128c + (rsub&31) + 64*(rsub>>5)
  const unsigned short* bP[2][2];
  size_t ebase = (size_t)e * 2 * NHID * NDIM;
#pragma unroll
  for (int g = 0; g < 2; ++g)
#pragma unroll
    for (int c = 0; c < 2; ++c) {
      int r = 32 * g + 128 * c + (rsub & 31) + 64 * (rsub >> 5);
      bP[g][c] = wBt + ebase + (size_t)(n0c + r) * NDIM + (swb >> 1);
    }
  // LDS dest bases (wave-uniform; HW adds lane*16)
  int aD0 = w * 1024;                                   // + 8192*g + 16384*c
  int bD0 = (w & 3) * 1024 + 8192 * (w >> 2);           // + 4096*g + 16384*c

  f32x4 acc[8][4];
#pragma unroll
  for (int m = 0; m < 8; ++m)
#pragma unroll
    for (int n = 0; n < 4; ++n) acc[m][n] = (f32x4)0.f;

  int wr = (w >> 2) * 128, wc = (w & 3) * 64;

  short8 ar[8], br0[4], br1[4];

  auto stageA = [&](int g, int kt, int buf) {
#pragma unroll
    for (int c = 0; c < 2; ++c)
      gload16(aP[g][c] + kt * 64, (char*)As[buf] + 8192 * g + 16384 * c + aD0);
  };
  auto stageB = [&](int g, int kt, int buf) {
#pragma unroll
    for (int c = 0; c < 2; ++c)
      gload16(bP[g][c] + kt * 64, (char*)Bs[buf] + 4096 * g + 16384 * c + bD0);
  };
  auto rdA = [&](const char* A, int mh) {
#pragma unroll
    for (int ks = 0; ks < 2; ++ks) {
      int kb = ks * 64 + ((l >> 4) << 4);
#pragma unroll
      for (int m = 0; m < 4; ++m) {
        int r = wr + mh * 64 + m * 16 + (l & 15);
        ar[ks * 4 + m] = *(const short8*)(A + r * 128 + (kb ^ ((r & 7) << 4)));
      }
    }
  };
  auto rdB = [&](const char* B, int nh, short8* br) {
#pragma unroll
    for (int ks = 0; ks < 2; ++ks) {
      int kb = ks * 64 + ((l >> 4) << 4);
#pragma unroll
      for (int n = 0; n < 2; ++n) {
        int r = wc + nh * 32 + n * 16 + (l & 15);
        br[ks * 2 + n] = *(const short8*)(B + r * 128 + (kb ^ ((r & 7) << 4)));
      }
    }
  };
  auto quad = [&](int mh, int nh, const short8* br) {
    __builtin_amdgcn_s_setprio(1);
#pragma unroll
    for (int ks = 0; ks < 2; ++ks)
#pragma unroll
      for (int m = 0; m < 4; ++m)
#pragma unroll
        for (int n = 0; n < 2; ++n)
          acc[mh * 4 + m][nh * 2 + n] = __builtin_amdgcn_mfma_f32_16x16x32_bf16(
              ar[ks * 4 + m], br[ks * 2 + n], acc[mh * 4 + m][nh * 2 + n], 0, 0, 0);
    __builtin_amdgcn_s_setprio(0);
  };

  // Prologue: tile 0 -> buf0, order [A0, B0, A1, B1].
  stageA(0, 0, 0);
  stageB(0, 0, 0);
  stageA(1, 0, 0);
  stageB(1, 0, 0);

  for (int t = 0; t < 15; ++t) {
    int cur = t & 1, nb = cur ^ 1;
    int ktN = t + 1;
    const char* A = (const char*)As[cur];
    const char* B = (const char*)Bs[cur];

    // P1
    stageA(0, ktN, nb);
    asm volatile("s_waitcnt vmcnt(6)" ::: "memory");
    __builtin_amdgcn_s_barrier();
    rdA(A, 0);
    rdB(B, 0, br0);
    quad(0, 0, br0);
    // P2
    stageB(0, ktN, nb);
    asm volatile("s_waitcnt vmcnt(4)" ::: "memory");
    __builtin_amdgcn_s_barrier();
    rdB(B, 1, br1);
    quad(0, 1, br1);
    // P3
    stageA(1, ktN, nb);
    __builtin_amdgcn_s_barrier();
    rdA(A, 1);
    quad(1, 1, br1);
    // P4
    stageB(1, ktN, nb);
    __builtin_amdgcn_s_barrier();
    quad(1, 0, br0);
  }

  // Tail tile 15 (buf1), no staging; tightened waits.
  {
    const char* A = (const char*)As[1];
    const char* B = (const char*)Bs[1];
    asm volatile("s_waitcnt vmcnt(4)" ::: "memory");
    __builtin_amdgcn_s_barrier();
    rdA(A, 0);
    rdB(B, 0, br0);
    quad(0, 0, br0);
    asm volatile("s_waitcnt vmcnt(0)" ::: "memory");
    __builtin_amdgcn_s_barrier();
    rdB(B, 1, br1);
    quad(0, 1, br1);
    __builtin_amdgcn_s_barrier();
    rdA(A, 1);
    quad(1, 1, br1);
    __builtin_amdgcn_s_barrier();
    quad(1, 0, br0);
  }

  // Epilogue: n even = XW1, n odd = XW2 for hid group (bx*8 + (w&3)*2 + nh).
  int gg0 = blockIdx.x * 8 + (w & 3) * 2;
#pragma unroll
  for (int m = 0; m < 8; ++m)
#pragma unroll
    for (int nh = 0; nh < 2; ++nh) {
      int hcol = (gg0 + nh) * 16 + (l & 15);
#pragma unroll
      for (int q = 0; q < 4; ++q) {
        int slot = m0 + wr + m * 16 + ((l >> 4) << 2) + q;
        float hv = silu(acc[m][nh * 2 + 0][q]) * acc[m][nh * 2 + 1][q];
        H[(size_t)slot * NHID + hcol] = f2bf(hv);
      }
    }
}

// ---------------------------------------------------------------------------
// GEMM3 (frozen champion): 128x128 tile, single-buffer 32 KiB, K=2048,
// T2 swizzle; grid x = n-fast. Gated atomicAdd epilogue.
// ---------------------------------------------------------------------------
__global__ __launch_bounds__(256, 2) void k_gemm3(
    const unsigned short* __restrict__ H, const unsigned short* __restrict__ w3t,
    float* __restrict__ out, const unsigned int* __restrict__ tok_list,
    const float* __restrict__ gate_list, const unsigned int* __restrict__ tile_e,
    const unsigned int* __restrict__ tile_m0) {
  unsigned int e = tile_e[blockIdx.y >> 1];
  if (e > 7u) return;
  int m0 = (int)tile_m0[blockIdx.y >> 1] + (int)(blockIdx.y & 1) * 128;
  int n0 = blockIdx.x * 128;

  __shared__ unsigned short As[128 * 64];
  __shared__ unsigned short Bs[128 * 64];

  int tid = threadIdx.x, w = tid >> 6, l = tid & 63;
  int rsub = tid >> 3;
  int swb = ((tid & 7) * 16) ^ ((rsub & 7) << 4);

  const unsigned short* aS[4];
  const unsigned short* bS[4];
#pragma unroll
  for (int jj = 0; jj < 4; ++jj) {
    int row = jj * 32 + rsub;
    aS[jj] = H + (size_t)(m0 + row) * NHID + (swb >> 1);
    bS[jj] = w3t + ((size_t)e * NDIM + n0 + row) * NHID + (swb >> 1);
  }
  int ldsb = w * 1024;

  f32x4 acc[4][4];
#pragma unroll
  for (int m = 0; m < 4; ++m)
#pragma unroll
    for (int n = 0; n < 4; ++n) acc[m][n] = (f32x4)0.f;

  int wr = (w >> 1) * 64, wc = (w & 1) * 64;

  for (int t = 0; t < 32; ++t) {
    int ke = t * 64;
#pragma unroll
    for (int jj = 0; jj < 4; ++jj) {
      gload16(aS[jj] + ke, (char*)As + jj * 4096 + ldsb);
      gload16(bS[jj] + ke, (char*)Bs + jj * 4096 + ldsb);
    }
    __syncthreads();
#pragma unroll
    for (int ks = 0; ks < 2; ++ks) {
      int kb = ks * 64 + ((l >> 4) << 4);
      short8 a[4], b[4];
#pragma unroll
      for (int m = 0; m < 4; ++m) {
        int r = wr + m * 16 + (l & 15);
        a[m] = *(const short8*)((const char*)As + r * 128 + (kb ^ ((r & 7) << 4)));
      }
#pragma unroll
      for (int n = 0; n < 4; ++n) {
        int r = wc + n * 16 + (l & 15);
        b[n] = *(const short8*)((const char*)Bs + r * 128 + (kb ^ ((r & 7) << 4)));
      }
#pragma unroll
      for (int m = 0; m < 4; ++m)
#pragma unroll
        for (int n = 0; n < 4; ++n)
          acc[m][n] = __builtin_amdgcn_mfma_f32_16x16x32_bf16(a[m], b[n], acc[m][n], 0, 0, 0);
    }
    __syncthreads();
  }

#pragma unroll
  for (int m = 0; m < 4; ++m)
#pragma unroll
    for (int q = 0; q < 4; ++q) {
      int slot = m0 + wr + m * 16 + ((l >> 4) << 2) + q;
      unsigned int tok = tok_list[slot];
      float g = gate_list[slot];
      if (g != 0.f) {
        float* orow = out + (size_t)tok * NDIM + n0 + wc;
#pragma unroll
        for (int n = 0; n < 4; ++n)
          atomicAdd(orow + n * 16 + (l & 15), acc[m][n][q] * g);
      }
    }
}

// ---------------------------------------------------------------------------
extern "C" void kernel_launch(void* const* d_in, const int* in_sizes, int n_in,
                              void* d_out, int out_size, void* d_ws, size_t ws_size,
                              hipStream_t stream) {
  const float* x = (const float*)d_in[0];
  const float* rw = (const float*)d_in[1];
  const float* w1 = (const float*)d_in[2];
  const float* w2 = (const float*)d_in[3];
  const float* w3 = (const float*)d_in[4];
  float* out = (float*)d_out;
  char* ws = (char*)d_ws;

  size_t o = 0;
  auto alloc = [&](size_t b) { size_t r = o; o = (o + b + 255) & ~(size_t)255; return r; };
  size_t o_xbf = alloc((size_t)TTOK * NDIM * 2);
  size_t o_w3t = alloc((size_t)NEXP * NDIM * NHID * 2);
  size_t o_H = alloc((size_t)SLOTCAP * NHID * 2);
  size_t o_tok = alloc((size_t)SLOTCAP * 4);
  size_t o_gate = alloc((size_t)SLOTCAP * 4);
  size_t o_te = alloc((size_t)TTOK * 2 * 4);
  size_t o_tg = alloc((size_t)TTOK * 2 * 4);
  size_t o_cnt = alloc(64);
  size_t o_cnt2 = alloc(64);
  size_t o_sb = alloc(64);
  size_t o_tle = alloc(MAXT * 4 + 64);
  size_t o_tlm = alloc(MAXT * 4 + 64);
  size_t need = o;

  size_t outBytes = (size_t)out_size * sizeof(float);
  size_t wtBytes = (size_t)NEXP * NDIM * NHID * 2;  // 32 MiB each

  if (ws_size < need || outBytes < 2 * wtBytes) {
    hipMemsetAsync(d_out, 0, outBytes, stream);
    k_sentinel<<<1, 64, 0, stream>>>(out, (float)((double)ws_size / 1048576.0));
    return;
  }

  unsigned short* xbf = (unsigned short*)(ws + o_xbf);
  unsigned short* w3t = (unsigned short*)(ws + o_w3t);
  unsigned short* Hbuf = (unsigned short*)(ws + o_H);
  unsigned int* tok_list = (unsigned int*)(ws + o_tok);
  float* gate_list = (float*)(ws + o_gate);
  int* tok_e = (int*)(ws + o_te);
  float* tok_gw = (float*)(ws + o_tg);
  unsigned int* counts = (unsigned int*)(ws + o_cnt);
  unsigned int* cnt2 = (unsigned int*)(ws + o_cnt2);
  unsigned int* slotbase = (unsigned int*)(ws + o_sb);
  unsigned int* tile_e = (unsigned int*)(ws + o_tle);
  unsigned int* tile_m0 = (unsigned int*)(ws + o_tlm);

  unsigned short* wBt = (unsigned short*)d_out;  // 64 MiB combined W1||W2 (pre-gemm3 scratch)

  hipMemsetAsync(counts, 0, 64, stream);
  hipMemsetAsync(tok_list, 0, (size_t)SLOTCAP * 4, stream);
  hipMemsetAsync(gate_list, 0, (size_t)SLOTCAP * 4, stream);

  k_prep<<<16384, 256, 0, stream>>>(x, rw, xbf, tok_e, tok_gw, w1, w2, w3, wBt, w3t);
  k_count<<<64, 256, 0, stream>>>(tok_e, counts);
  k_offsets<<<1, 64, 0, stream>>>(counts, slotbase, cnt2, tile_e, tile_m0);
  k_fill<<<TTOK / 256, 256, 0, stream>>>(tok_e, tok_gw, slotbase, cnt2, tok_list, gate_list);

  k_gemm12<<<dim3(2 * NHID / 256, MAXT), 512, 0, stream>>>(xbf, wBt, Hbuf, tok_list,
                                                           tile_e, tile_m0);

  hipMemsetAsync(d_out, 0, outBytes, stream);

  k_gemm3<<<dim3(NDIM / 128, 2 * MAXT), 256, 0, stream>>>(Hbuf, w3t, out, tok_list, gate_list,
                                                          tile_e, tile_m0);
}

// Round 17
// 668.649 us; speedup vs baseline: 1.0393x; 1.0393x over previous
//
#include <hip/hip_runtime.h>
#include <stdint.h>

#define TTOK 16384
#define NDIM 1024
#define NHID 2048
#define NEXP 8
#define TM 256
#define MAXT 136
#define SLOTCAP (2 * TTOK + NEXP * TM) /* 34816 */

typedef __attribute__((ext_vector_type(8))) short short8;
typedef __attribute__((ext_vector_type(4))) float f32x4;

__device__ __forceinline__ unsigned short f2bf(float f) {
  unsigned int u = __float_as_uint(f);
  u += 0x7FFFu + ((u >> 16) & 1u);
  return (unsigned short)(u >> 16);
}

__device__ __forceinline__ void gload16(const void* g, void* l) {
  __builtin_amdgcn_global_load_lds(
      (const __attribute__((address_space(1))) unsigned int*)g,
      (__attribute__((address_space(3))) unsigned int*)l, 16, 0, 0);
}

__device__ __forceinline__ float silu(float z) {
  return z / (1.0f + __expf(-z));
}

// ---------------------------------------------------------------------------
// k_prep: merged router + weight transpose/convert.
// Blocks 0..4095 = router (4 tokens each); 4096..16383 = tconv.
// ---------------------------------------------------------------------------
__device__ __forceinline__ void router_block(int b, const float* __restrict__ x,
                                             const float* __restrict__ rw,
                                             unsigned short* __restrict__ xbf,
                                             int* __restrict__ tok_e,
                                             float* __restrict__ tok_gw) {
  int t = (b << 2) + (threadIdx.x >> 6);
  int lane = threadIdx.x & 63;
  const float4* xr = (const float4*)(x + (size_t)t * NDIM);

  float4 v[4];
  float d[NEXP];
#pragma unroll
  for (int e = 0; e < NEXP; ++e) d[e] = 0.f;

#pragma unroll
  for (int i = 0; i < 4; ++i) {
    int c = i * 64 + lane;
    v[i] = xr[c];
#pragma unroll
    for (int e = 0; e < NEXP; ++e) {
      float4 w = ((const float4*)(rw + e * NDIM))[c];
      d[e] += v[i].x * w.x + v[i].y * w.y + v[i].z * w.z + v[i].w * w.w;
    }
  }
#pragma unroll
  for (int e = 0; e < NEXP; ++e)
    for (int s = 32; s; s >>= 1) d[e] += __shfl_xor(d[e], s, 64);

  unsigned short* xo = xbf + (size_t)t * NDIM;
#pragma unroll
  for (int i = 0; i < 4; ++i) {
    int c = i * 64 + lane;
    ushort4 u;
    u.x = f2bf(v[i].x); u.y = f2bf(v[i].y); u.z = f2bf(v[i].z); u.w = f2bf(v[i].w);
    ((ushort4*)xo)[c] = u;
  }

  if (lane == 0) {
    float m = d[0];
#pragma unroll
    for (int e = 1; e < NEXP; ++e) m = fmaxf(m, d[e]);
    float ex[NEXP];
#pragma unroll
    for (int e = 0; e < NEXP; ++e) ex[e] = __expf(d[e] - m);
    int e0 = 0;
#pragma unroll
    for (int e = 1; e < NEXP; ++e) if (ex[e] > ex[e0]) e0 = e;
    int e1 = (e0 == 0) ? 1 : 0;
#pragma unroll
    for (int e = 0; e < NEXP; ++e) if (e != e0 && ex[e] > ex[e1]) e1 = e;
    float p0 = ex[e0], p1 = ex[e1];
    float inv = 1.f / (p0 + p1);
    tok_e[2 * t] = e0; tok_e[2 * t + 1] = e1;
    tok_gw[2 * t] = p0 * inv; tok_gw[2 * t + 1] = p1 * inv;
  }
}

__device__ __forceinline__ void tconv_tile(const float* __restrict__ src,
                                           unsigned short* __restrict__ dst,
                                           int R, int C, int bx, int by) {
  __shared__ unsigned short tile[64][65];
  int tx = threadIdx.x & 15, ty = threadIdx.x >> 4;
#pragma unroll
  for (int rr = 0; rr < 4; ++rr) {
    int rl = rr * 16 + ty;
    float4 v = *(const float4*)(src + (size_t)(by + rl) * C + bx + tx * 4);
    tile[rl][tx * 4 + 0] = f2bf(v.x);
    tile[rl][tx * 4 + 1] = f2bf(v.y);
    tile[rl][tx * 4 + 2] = f2bf(v.z);
    tile[rl][tx * 4 + 3] = f2bf(v.w);
  }
  __syncthreads();
#pragma unroll
  for (int rr = 0; rr < 4; ++rr) {
    int cl = rr * 16 + ty;
    ushort4 u;
    u.x = tile[tx * 4 + 0][cl];
    u.y = tile[tx * 4 + 1][cl];
    u.z = tile[tx * 4 + 2][cl];
    u.w = tile[tx * 4 + 3][cl];
    *(ushort4*)(dst + (size_t)(bx + cl) * R + by + tx * 4) = u;
  }
}

__global__ void k_prep(const float* __restrict__ x, const float* __restrict__ rw,
                       unsigned short* __restrict__ xbf, int* __restrict__ tok_e,
                       float* __restrict__ tok_gw, const float* __restrict__ w1,
                       const float* __restrict__ w2, const float* __restrict__ w3,
                       unsigned short* __restrict__ w1t, unsigned short* __restrict__ w2t,
                       unsigned short* __restrict__ w3t) {
  int b = blockIdx.x;
  if (b < 4096) {
    router_block(b, x, rw, xbf, tok_e, tok_gw);
    return;
  }
  int tcb = b - 4096;
  int bx = tcb & 31;
  int by = (tcb >> 5) & 15;
  int z = tcb >> 9;
  if (z < 16) {
    int e = z & 7;
    const float* src = (z < 8 ? w1 : w2) + (size_t)e * NDIM * NHID;
    unsigned short* dst = (z < 8 ? w1t : w2t) + (size_t)e * NDIM * NHID;
    tconv_tile(src, dst, NDIM, NHID, bx * 64, by * 64);
  } else {
    int e = z - 16;
    const float* src = w3 + (size_t)e * NHID * NDIM;
    unsigned short* dst = w3t + (size_t)e * NHID * NDIM;
    tconv_tile(src, dst, NHID, NDIM, by * 64, bx * 64);
  }
}

// ---------------------------------------------------------------------------
// Count / Offsets / Fill (frozen).
// ---------------------------------------------------------------------------
__global__ void k_count(const int* __restrict__ tok_e, unsigned int* __restrict__ counts) {
  __shared__ unsigned int h[NEXP];
  int tid = threadIdx.x;
  if (tid < NEXP) h[tid] = 0u;
  __syncthreads();
  for (int i = blockIdx.x * 256 + tid; i < 2 * TTOK; i += gridDim.x * 256)
    atomicAdd(&h[tok_e[i]], 1u);
  __syncthreads();
  if (tid < NEXP) atomicAdd(&counts[tid], h[tid]);
}

__global__ void k_offsets(const unsigned int* __restrict__ counts,
                          unsigned int* __restrict__ slotbase, unsigned int* __restrict__ cnt2,
                          unsigned int* __restrict__ tile_e, unsigned int* __restrict__ tile_m0) {
  int l = threadIdx.x;
  unsigned int c[NEXP], base[NEXP], tb[NEXP];
  unsigned int b = 0, t = 0;
#pragma unroll
  for (int e = 0; e < NEXP; ++e) {
    c[e] = counts[e];
    base[e] = b; tb[e] = t;
    unsigned int nt = (c[e] + TM - 1) / TM;
    b += nt * TM; t += nt;
  }
  if (l < NEXP) { slotbase[l] = base[l]; cnt2[l] = 0u; }
  for (int idx = l; idx < MAXT; idx += 64) {
    unsigned int te = 0xFFFFFFFFu, tm = 0;
#pragma unroll
    for (int e = 0; e < NEXP; ++e) {
      unsigned int nt = (c[e] + TM - 1) / TM;
      if ((unsigned)idx >= tb[e] && (unsigned)idx < tb[e] + nt) {
        te = (unsigned)e; tm = base[e] + ((unsigned)idx - tb[e]) * TM;
      }
    }
    tile_e[idx] = te; tile_m0[idx] = tm;
  }
}

__global__ void k_fill(const int* __restrict__ tok_e, const float* __restrict__ tok_gw,
                       const unsigned int* __restrict__ slotbase, unsigned int* __restrict__ cnt2,
                       unsigned int* __restrict__ tok_list, float* __restrict__ gate_list) {
  __shared__ unsigned int hcnt[NEXP];
  __shared__ unsigned int hbase[NEXP];
  int tid = threadIdx.x;
  int t = blockIdx.x * 256 + tid;
  if (tid < NEXP) hcnt[tid] = 0u;
  __syncthreads();
  int e0 = tok_e[2 * t], e1 = tok_e[2 * t + 1];
  float g0 = tok_gw[2 * t], g1 = tok_gw[2 * t + 1];
  unsigned int p0 = atomicAdd(&hcnt[e0], 1u);
  unsigned int p1 = atomicAdd(&hcnt[e1], 1u);
  __syncthreads();
  if (tid < NEXP) hbase[tid] = atomicAdd(&cnt2[tid], hcnt[tid]);
  __syncthreads();
  unsigned int s0 = slotbase[e0] + hbase[e0] + p0;
  unsigned int s1 = slotbase[e1] + hbase[e1] + p1;
  tok_list[s0] = (unsigned)t; gate_list[s0] = g0;
  tok_list[s1] = (unsigned)t; gate_list[s1] = g1;
}

__global__ void k_sentinel(float* __restrict__ out, float v) {
  if (threadIdx.x == 0 && blockIdx.x == 0) out[0] = v;
}

// ---------------------------------------------------------------------------
// GEMM12 (champion, measured 381us x3): BM=256, BN=128 dual-B, BK=64,
// 8 waves, 2-slot dbuf 128 KiB, T2 swizzle, x=n-fast; fine-phase schedule
// (4 phases x {ds_read | stage 2 chunks -> s_barrier -> setprio(1) 16-MFMA}),
// one vmcnt(0) checkpoint per K-tile.
// True reg footprint = 112 arch + 128 acc ~= 240 -> 2 waves/SIMD, 1 blk/CU.
// Schedule-space swept (6 variants, R6-R16): all 381-435us -> structural
// plateau; do not retune schedule, occupancy (R7/R11/R14), or MFMA shape
// (32x32 -> 4-way LDS conflict) on this geometry.
// ---------------------------------------------------------------------------
__global__ __launch_bounds__(512, 2) void k_gemm12(
    const unsigned short* __restrict__ xbf, const unsigned short* __restrict__ w1t,
    const unsigned short* __restrict__ w2t, unsigned short* __restrict__ H,
    const unsigned int* __restrict__ tok_list, const unsigned int* __restrict__ tile_e,
    const unsigned int* __restrict__ tile_m0) {
  unsigned int e = tile_e[blockIdx.y];
  if (e > 7u) return;
  int m0 = (int)tile_m0[blockIdx.y];
  int n0 = blockIdx.x * 128;

  __shared__ unsigned short As[2][256 * 64];
  __shared__ unsigned short B1s[2][128 * 64];
  __shared__ unsigned short B2s[2][128 * 64];

  int tid = threadIdx.x, w = tid >> 6, l = tid & 63;
  int rsub = tid >> 3;
  int swb = ((tid & 7) * 16) ^ ((rsub & 7) << 4);

  const unsigned short* aS[4];
#pragma unroll
  for (int jj = 0; jj < 4; ++jj) {
    int row = jj * 64 + rsub;
    aS[jj] = xbf + (size_t)tok_list[m0 + row] * NDIM + (swb >> 1);
  }
  const unsigned short* b1S[2];
  const unsigned short* b2S[2];
#pragma unroll
  for (int jj = 0; jj < 2; ++jj) {
    int row = jj * 64 + rsub;
    size_t off = ((size_t)e * NHID + n0 + row) * NDIM + (swb >> 1);
    b1S[jj] = w1t + off;
    b2S[jj] = w2t + off;
  }
  int ldsb = w * 1024;

  f32x4 acc1[8][2], acc2[8][2];
#pragma unroll
  for (int m = 0; m < 8; ++m)
#pragma unroll
    for (int n = 0; n < 2; ++n) { acc1[m][n] = (f32x4)0.f; acc2[m][n] = (f32x4)0.f; }

  int wr = (w >> 2) * 128, wc = (w & 3) * 32;

#pragma unroll
  for (int jj = 0; jj < 4; ++jj)
    gload16(aS[jj], (char*)As[0] + jj * 8192 + ldsb);
#pragma unroll
  for (int jj = 0; jj < 2; ++jj) {
    gload16(b1S[jj], (char*)B1s[0] + jj * 8192 + ldsb);
    gload16(b2S[jj], (char*)B2s[0] + jj * 8192 + ldsb);
  }

  for (int t = 0; t < 16; ++t) {
    int cur = t & 1, nxt = cur ^ 1;
    int keN = (t + 1) * 64;
    bool st = (t < 15);
    const char* A = (const char*)As[cur];
    const char* B1 = (const char*)B1s[cur];
    const char* B2 = (const char*)B2s[cur];
    char* An = (char*)As[nxt];
    char* B1n = (char*)B1s[nxt];
    char* B2n = (char*)B2s[nxt];

    asm volatile("s_waitcnt vmcnt(0)" ::: "memory");
    __builtin_amdgcn_s_barrier();
    __builtin_amdgcn_sched_barrier(0);

    short8 ar[8], b1r[4], b2r[4];

    // ---- P0: read a(mh0) + b1; stage A0,A1 of t+1; MFMA acc1 mh0 ----
#pragma unroll
    for (int ks = 0; ks < 2; ++ks) {
      int kb = ks * 64 + ((l >> 4) << 4);
#pragma unroll
      for (int m = 0; m < 4; ++m) {
        int r = wr + m * 16 + (l & 15);
        ar[ks * 4 + m] = *(const short8*)(A + r * 128 + (kb ^ ((r & 7) << 4)));
      }
#pragma unroll
      for (int n = 0; n < 2; ++n) {
        int r = wc + n * 16 + (l & 15);
        b1r[ks * 2 + n] = *(const short8*)(B1 + r * 128 + (kb ^ ((r & 7) << 4)));
      }
    }
    if (st) {
      gload16(aS[0] + keN, An + 0 * 8192 + ldsb);
      gload16(aS[1] + keN, An + 1 * 8192 + ldsb);
    }
    __builtin_amdgcn_s_barrier();
    __builtin_amdgcn_s_setprio(1);
#pragma unroll
    for (int ks = 0; ks < 2; ++ks)
#pragma unroll
      for (int m = 0; m < 4; ++m)
#pragma unroll
        for (int n = 0; n < 2; ++n)
          acc1[m][n] = __builtin_amdgcn_mfma_f32_16x16x32_bf16(ar[ks * 4 + m], b1r[ks * 2 + n],
                                                              acc1[m][n], 0, 0, 0);
    __builtin_amdgcn_s_setprio(0);

    // ---- P1: read b2; stage A2,A3; MFMA acc2 mh0 ----
#pragma unroll
    for (int ks = 0; ks < 2; ++ks) {
      int kb = ks * 64 + ((l >> 4) << 4);
#pragma unroll
      for (int n = 0; n < 2; ++n) {
        int r = wc + n * 16 + (l & 15);
        b2r[ks * 2 + n] = *(const short8*)(B2 + r * 128 + (kb ^ ((r & 7) << 4)));
      }
    }
    if (st) {
      gload16(aS[2] + keN, An + 2 * 8192 + ldsb);
      gload16(aS[3] + keN, An + 3 * 8192 + ldsb);
    }
    __builtin_amdgcn_s_barrier();
    __builtin_amdgcn_s_setprio(1);
#pragma unroll
    for (int ks = 0; ks < 2; ++ks)
#pragma unroll
      for (int m = 0; m < 4; ++m)
#pragma unroll
        for (int n = 0; n < 2; ++n)
          acc2[m][n] = __builtin_amdgcn_mfma_f32_16x16x32_bf16(ar[ks * 4 + m], b2r[ks * 2 + n],
                                                              acc2[m][n], 0, 0, 0);
    __builtin_amdgcn_s_setprio(0);

    // ---- P2: read a(mh1); stage B1x2; MFMA acc1 mh1 ----
#pragma unroll
    for (int ks = 0; ks < 2; ++ks) {
      int kb = ks * 64 + ((l >> 4) << 4);
#pragma unroll
      for (int m = 0; m < 4; ++m) {
        int r = wr + 64 + m * 16 + (l & 15);
        ar[ks * 4 + m] = *(const short8*)(A + r * 128 + (kb ^ ((r & 7) << 4)));
      }
    }
    if (st) {
      gload16(b1S[0] + keN, B1n + 0 * 8192 + ldsb);
      gload16(b1S[1] + keN, B1n + 1 * 8192 + ldsb);
    }
    __builtin_amdgcn_s_barrier();
    __builtin_amdgcn_s_setprio(1);
#pragma unroll
    for (int ks = 0; ks < 2; ++ks)
#pragma unroll
      for (int m = 0; m < 4; ++m)
#pragma unroll
        for (int n = 0; n < 2; ++n)
          acc1[4 + m][n] = __builtin_amdgcn_mfma_f32_16x16x32_bf16(ar[ks * 4 + m], b1r[ks * 2 + n],
                                                                  acc1[4 + m][n], 0, 0, 0);
    __builtin_amdgcn_s_setprio(0);

    // ---- P3: stage B2x2; MFMA acc2 mh1 (reuse ar, b2r) ----
    if (st) {
      gload16(b2S[0] + keN, B2n + 0 * 8192 + ldsb);
      gload16(b2S[1] + keN, B2n + 1 * 8192 + ldsb);
    }
    __builtin_amdgcn_s_barrier();
    __builtin_amdgcn_s_setprio(1);
#pragma unroll
    for (int ks = 0; ks < 2; ++ks)
#pragma unroll
      for (int m = 0; m < 4; ++m)
#pragma unroll
        for (int n = 0; n < 2; ++n)
          acc2[4 + m][n] = __builtin_amdgcn_mfma_f32_16x16x32_bf16(ar[ks * 4 + m], b2r[ks * 2 + n],
                                                                  acc2[4 + m][n], 0, 0, 0);
    __builtin_amdgcn_s_setprio(0);
  }

#pragma unroll
  for (int m = 0; m < 8; ++m)
#pragma unroll
    for (int n = 0; n < 2; ++n) {
      int col = n0 + wc + n * 16 + (l & 15);
#pragma unroll
      for (int q = 0; q < 4; ++q) {
        int slot = m0 + wr + m * 16 + ((l >> 4) << 2) + q;
        float hv = silu(acc1[m][n][q]) * acc2[m][n][q];
        H[(size_t)slot * NHID + col] = f2bf(hv);
      }
    }
}

// ---------------------------------------------------------------------------
// GEMM3 (frozen champion): 128x128 tile, single-buffer 32 KiB, K=2048,
// T2 swizzle; grid x = n-fast. Gated atomicAdd epilogue.
// ---------------------------------------------------------------------------
__global__ __launch_bounds__(256, 2) void k_gemm3(
    const unsigned short* __restrict__ H, const unsigned short* __restrict__ w3t,
    float* __restrict__ out, const unsigned int* __restrict__ tok_list,
    const float* __restrict__ gate_list, const unsigned int* __restrict__ tile_e,
    const unsigned int* __restrict__ tile_m0) {
  unsigned int e = tile_e[blockIdx.y >> 1];
  if (e > 7u) return;
  int m0 = (int)tile_m0[blockIdx.y >> 1] + (int)(blockIdx.y & 1) * 128;
  int n0 = blockIdx.x * 128;

  __shared__ unsigned short As[128 * 64];
  __shared__ unsigned short Bs[128 * 64];

  int tid = threadIdx.x, w = tid >> 6, l = tid & 63;
  int rsub = tid >> 3;
  int swb = ((tid & 7) * 16) ^ ((rsub & 7) << 4);

  const unsigned short* aS[4];
  const unsigned short* bS[4];
#pragma unroll
  for (int jj = 0; jj < 4; ++jj) {
    int row = jj * 32 + rsub;
    aS[jj] = H + (size_t)(m0 + row) * NHID + (swb >> 1);
    bS[jj] = w3t + ((size_t)e * NDIM + n0 + row) * NHID + (swb >> 1);
  }
  int ldsb = w * 1024;

  f32x4 acc[4][4];
#pragma unroll
  for (int m = 0; m < 4; ++m)
#pragma unroll
    for (int n = 0; n < 4; ++n) acc[m][n] = (f32x4)0.f;

  int wr = (w >> 1) * 64, wc = (w & 1) * 64;

  for (int t = 0; t < 32; ++t) {
    int ke = t * 64;
#pragma unroll
    for (int jj = 0; jj < 4; ++jj) {
      gload16(aS[jj] + ke, (char*)As + jj * 4096 + ldsb);
      gload16(bS[jj] + ke, (char*)Bs + jj * 4096 + ldsb);
    }
    __syncthreads();
#pragma unroll
    for (int ks = 0; ks < 2; ++ks) {
      int kb = ks * 64 + ((l >> 4) << 4);
      short8 a[4], b[4];
#pragma unroll
      for (int m = 0; m < 4; ++m) {
        int r = wr + m * 16 + (l & 15);
        a[m] = *(const short8*)((const char*)As + r * 128 + (kb ^ ((r & 7) << 4)));
      }
#pragma unroll
      for (int n = 0; n < 4; ++n) {
        int r = wc + n * 16 + (l & 15);
        b[n] = *(const short8*)((const char*)Bs + r * 128 + (kb ^ ((r & 7) << 4)));
      }
#pragma unroll
      for (int m = 0; m < 4; ++m)
#pragma unroll
        for (int n = 0; n < 4; ++n)
          acc[m][n] = __builtin_amdgcn_mfma_f32_16x16x32_bf16(a[m], b[n], acc[m][n], 0, 0, 0);
    }
    __syncthreads();
  }

#pragma unroll
  for (int m = 0; m < 4; ++m)
#pragma unroll
    for (int q = 0; q < 4; ++q) {
      int slot = m0 + wr + m * 16 + ((l >> 4) << 2) + q;
      unsigned int tok = tok_list[slot];
      float g = gate_list[slot];
      if (g != 0.f) {
        float* orow = out + (size_t)tok * NDIM + n0 + wc;
#pragma unroll
        for (int n = 0; n < 4; ++n)
          atomicAdd(orow + n * 16 + (l & 15), acc[m][n][q] * g);
      }
    }
}

// ---------------------------------------------------------------------------
extern "C" void kernel_launch(void* const* d_in, const int* in_sizes, int n_in,
                              void* d_out, int out_size, void* d_ws, size_t ws_size,
                              hipStream_t stream) {
  const float* x = (const float*)d_in[0];
  const float* rw = (const float*)d_in[1];
  const float* w1 = (const float*)d_in[2];
  const float* w2 = (const float*)d_in[3];
  const float* w3 = (const float*)d_in[4];
  float* out = (float*)d_out;
  char* ws = (char*)d_ws;

  size_t o = 0;
  auto alloc = [&](size_t b) { size_t r = o; o = (o + b + 255) & ~(size_t)255; return r; };
  size_t o_xbf = alloc((size_t)TTOK * NDIM * 2);
  size_t o_w3t = alloc((size_t)NEXP * NDIM * NHID * 2);
  size_t o_H = alloc((size_t)SLOTCAP * NHID * 2);
  size_t o_tok = alloc((size_t)SLOTCAP * 4);
  size_t o_gate = alloc((size_t)SLOTCAP * 4);
  size_t o_te = alloc((size_t)TTOK * 2 * 4);
  size_t o_tg = alloc((size_t)TTOK * 2 * 4);
  size_t o_cnt = alloc(64);
  size_t o_cnt2 = alloc(64);
  size_t o_sb = alloc(64);
  size_t o_tle = alloc(MAXT * 4 + 64);
  size_t o_tlm = alloc(MAXT * 4 + 64);
  size_t need = o;

  size_t outBytes = (size_t)out_size * sizeof(float);
  size_t wtBytes = (size_t)NEXP * NDIM * NHID * 2;  // 32 MiB each

  if (ws_size < need || outBytes < 2 * wtBytes) {
    hipMemsetAsync(d_out, 0, outBytes, stream);
    k_sentinel<<<1, 64, 0, stream>>>(out, (float)((double)ws_size / 1048576.0));
    return;
  }

  unsigned short* xbf = (unsigned short*)(ws + o_xbf);
  unsigned short* w3t = (unsigned short*)(ws + o_w3t);
  unsigned short* Hbuf = (unsigned short*)(ws + o_H);
  unsigned int* tok_list = (unsigned int*)(ws + o_tok);
  float* gate_list = (float*)(ws + o_gate);
  int* tok_e = (int*)(ws + o_te);
  float* tok_gw = (float*)(ws + o_tg);
  unsigned int* counts = (unsigned int*)(ws + o_cnt);
  unsigned int* cnt2 = (unsigned int*)(ws + o_cnt2);
  unsigned int* slotbase = (unsigned int*)(ws + o_sb);
  unsigned int* tile_e = (unsigned int*)(ws + o_tle);
  unsigned int* tile_m0 = (unsigned int*)(ws + o_tlm);

  unsigned short* w1t = (unsigned short*)d_out;  // d_out as scratch pre-gemm3
  unsigned short* w2t = (unsigned short*)((char*)d_out + wtBytes);

  hipMemsetAsync(counts, 0, 64, stream);
  hipMemsetAsync(tok_list, 0, (size_t)SLOTCAP * 4, stream);
  hipMemsetAsync(gate_list, 0, (size_t)SLOTCAP * 4, stream);

  k_prep<<<16384, 256, 0, stream>>>(x, rw, xbf, tok_e, tok_gw, w1, w2, w3, w1t, w2t, w3t);
  k_count<<<64, 256, 0, stream>>>(tok_e, counts);
  k_offsets<<<1, 64, 0, stream>>>(counts, slotbase, cnt2, tile_e, tile_m0);
  k_fill<<<TTOK / 256, 256, 0, stream>>>(tok_e, tok_gw, slotbase, cnt2, tok_list, gate_list);

  k_gemm12<<<dim3(NHID / 128, MAXT), 512, 0, stream>>>(xbf, w1t, w2t, Hbuf, tok_list,
                                                       tile_e, tile_m0);

  hipMemsetAsync(d_out, 0, outBytes, stream);

  k_gemm3<<<dim3(NDIM / 128, 2 * MAXT), 256, 0, stream>>>(Hbuf, w3t, out, tok_list, gate_list,
                                                          tile_e, tile_m0);
}